// Round 1
// baseline (615.212 us; speedup 1.0000x reference)
//
#include <hip/hip_runtime.h>
#include <cstddef>

// Problem constants (fixed by the reference)
#define F       1024      // feature dim
#define NB      128       // batch (scan steps)
#define KK      4096      // RATE*F = GEMM K
#define KSPLIT  8
#define KCHUNK  512       // KK / KSPLIT
#define KT      32        // k-tile staged in LDS
#define BT      16        // b-tile per block
#define OT      256       // o-tile per block
#define NGEMM   256       // gemm blocks (4 ot x 8 bt x 8 ks)
#define NWRITE  32768     // bulk writer blocks (4 rows each)

typedef float f4 __attribute__((ext_vector_type(4)));
typedef float f2 __attribute__((ext_vector_type(2)));

// K1: GEMM blocks interleaved into the bulk-copy dispatch.
// Block IDs: bid < 1024 && (bid&3)==0 -> one of 256 GEMM blocks (all resident
// from t=0, ~1 per CU); everything else is a writer block. The GEMM's compute
// and load latency hide under the write-BW-bound 478 MiB stream-out.
// Writer blocks SKIP the comp-sourced conv rows (row >= 511-b); those are
// produced by comp_scatter after the partials are complete.
__global__ __launch_bounds__(256) void fused_bulk(
    const float* __restrict__ inputs, const float* __restrict__ mem,
    const float* __restrict__ kern, float* __restrict__ partial,
    float* __restrict__ out)
{
  __shared__ float At[KT][BT];  // A tile, transposed [k][b]
  __shared__ float Bt[KT][OT];  // kernel tile [k][o]
  const int bid = blockIdx.x;
  const int t   = threadIdx.x;

  if (bid < 4 * NGEMM && (bid & 3) == 0) {
    // ---- GEMM partial: comp_partial[ks][b][o] = sum_{k in chunk} A[b,k]*K[k,o]
    const int g  = bid >> 2;
    const int ot = g & 3, bt = (g >> 2) & 7, ks = g >> 5;
    const int tx = t & 63;        // 64 o-groups of 4 cols
    const int ty = t >> 6;        // 4 b-groups of 4 rows
    f4 acc[4] = {{0,0,0,0},{0,0,0,0},{0,0,0,0},{0,0,0,0}};
    const float* Ab = mem + 512 * F;   // A = (128 x 4096) row-major

    for (int kc = 0; kc < KCHUNK; kc += KT) {
      const int k0 = ks * KCHUNK + kc;
      // stage A: 16 rows x 32 k, transposed into LDS
      {
        const int b_l = t >> 4;          // 0..15
        const int k_l = (t & 15) * 2;    // 0..30 (even)
        f2 v = *(const f2*)(Ab + (size_t)(bt * BT + b_l) * KK + k0 + k_l);
        At[k_l][b_l]     = v.x;
        At[k_l + 1][b_l] = v.y;
      }
      // stage B: 32 k-rows x 256 cols = 2048 float4, 8 per thread (coalesced)
#pragma unroll
      for (int i = 0; i < 8; ++i) {
        const int fid = t + i * 256;
        const int r = fid >> 6, c4 = fid & 63;
        *(f4*)&Bt[r][c4 * 4] =
            *(const f4*)(kern + (size_t)(k0 + r) * F + ot * OT + c4 * 4);
      }
      __syncthreads();
#pragma unroll
      for (int k = 0; k < KT; ++k) {
        f4 a  = *(const f4*)&At[k][ty * 4];   // broadcast (wave shares ty)
        f4 bv = *(const f4*)&Bt[k][tx * 4];   // 64 consecutive f4 -> full rate
        acc[0] += a.x * bv;
        acc[1] += a.y * bv;
        acc[2] += a.z * bv;
        acc[3] += a.w * bv;
      }
      __syncthreads();
    }
    // normal (cached) stores: comp_scatter re-reads these from L2
    float* p = partial + ((size_t)ks * NB + bt * BT + ty * 4) * F + ot * OT + tx * 4;
#pragma unroll
    for (int i = 0; i < 4; ++i) *(f4*)(p + (size_t)i * F) = acc[i];
    return;
  }

  // ---- bulk writer: pure gather, 4 output rows per block, NT stores.
  const int w    = (bid < 4 * NGEMM) ? (bid - (bid >> 2) - 1) : (bid - NGEMM);
  const int base = w * 4;
#pragma unroll
  for (int r = 0; r < 4; ++r) {
    const int gid = base + r;
    const int b = gid >> 10, row = gid & 1023;
    const float* src;
    if (row < 512) {
      const int lim1 = 511 - b;                     // original conv rows kept
      if (row >= lim1) continue;                    // comp row -> comp_scatter
      src = mem + (size_t)(b + 1 + row) * F;
    } else {
      const int r2 = row - 512;
      const int c2 = 508 - 4 * b;                   // original short rows kept
      src = (r2 < c2) ? (mem + (size_t)(516 + 4 * b + r2) * F)
                      : (inputs + (size_t)(r2 - c2) * F);
    }
    const f4 v = *(const f4*)(src + t * 4);
    __builtin_nontemporal_store(v, (f4*)(out + (size_t)gid * F + t * 4));
  }
}

// K2: reduce the KSPLIT partials for comp row c in-register (same FP order as
// the old reduce_comp: bias first, then ks ascending -> bit-identical), then
// NT-scatter that row to every output sample that contains it:
//   out[b][511-b+c] = comp[c]  for all b >= c.
// grid: 1024 blocks = (c: 128) x (jb: 8 chunks of 16 b-values).
__global__ __launch_bounds__(256) void comp_scatter(
    const float* __restrict__ partial, const float* __restrict__ bias,
    float* __restrict__ out)
{
  const int bid = blockIdx.x;
  const int c  = bid >> 3;        // comp row 0..127
  const int jb = bid & 7;         // b-chunk
  const int b0 = jb * 16;
  if (b0 + 15 < c) return;        // no b >= c in this chunk

  const int t = threadIdx.x;
  f4 s = *(const f4*)(bias + t * 4);
#pragma unroll
  for (int ks = 0; ks < KSPLIT; ++ks)
    s += *(const f4*)(partial + ((size_t)ks * NB + c) * F + t * 4);

  const int blo = (b0 > c) ? b0 : c;
  const int bhi = (b0 + 15 < 127) ? (b0 + 15) : 127;
  for (int b = blo; b <= bhi; ++b) {
    float* dst = out + ((size_t)b * 1024 + (511 - b + c)) * F + t * 4;
    __builtin_nontemporal_store(s, (f4*)dst);
  }
}

extern "C" void kernel_launch(void* const* d_in, const int* in_sizes, int n_in,
                              void* d_out, int out_size, void* d_ws, size_t ws_size,
                              hipStream_t stream) {
  const float* inputs = (const float*)d_in[0];   // (128,4,1024)
  const float* memory = (const float*)d_in[1];   // (1024,1024)
  const float* kern   = (const float*)d_in[2];   // (4,1024,1024)
  const float* bias   = (const float*)d_in[3];   // (1024,)
  float* out = (float*)d_out;                    // (128,1024,1024)

  float* partial = (float*)d_ws;                 // KSPLIT*128*1024 floats = 4 MiB

  fused_bulk<<<dim3(NWRITE + NGEMM), 256, 0, stream>>>(inputs, memory, kern,
                                                       partial, out);
  comp_scatter<<<dim3(1024), 256, 0, stream>>>(partial, bias, out);
}

// Round 2
// 589.078 us; speedup vs baseline: 1.0444x; 1.0444x over previous
//
#include <hip/hip_runtime.h>
#include <cstddef>

// Problem constants (fixed by the reference)
#define F       1024      // feature dim
#define NB      128       // batch (scan steps)
#define KK      4096      // RATE*F = GEMM K
#define KSPLIT  8         // DO NOT CHANGE: k-chunk boundaries fix FP order
#define KCHUNK  512       // KK / KSPLIT
#define KT      16        // k-tile staged in LDS (16 -> 18KB LDS, 8 blocks/CU)
#define BT      32        // b-tile per block (32 -> kern re-fetch 64MB not 128MB)
#define OT      256       // o-tile per block
#define NGEMM   128       // gemm blocks (4 ot x 4 bt x 8 ks), prefix of grid
#define NWRITE  32768     // bulk writer blocks (4 rows each)

typedef float f4 __attribute__((ext_vector_type(4)));
typedef float f2 __attribute__((ext_vector_type(2)));

// K1: GEMM blocks fused into the bulk-copy dispatch as grid prefix.
// bids 0..127 -> GEMM partial blocks (~1 per CU on half the CUs, resident from
// t=0, latency hidden under the write-BW-bound 478 MiB stream-out).
// LDS = 18 KB <= 20 KB so writer occupancy stays at the thread-limit
// (8 blocks/CU, 32 waves) -- round 1's 34 KB halved it and cost +44 us.
// Writer blocks SKIP comp-sourced conv rows; comp_scatter produces those.
__global__ __launch_bounds__(256) void fused_bulk(
    const float* __restrict__ inputs, const float* __restrict__ mem,
    const float* __restrict__ kern, float* __restrict__ partial,
    float* __restrict__ out)
{
  __shared__ float At[KT][BT];  // A tile, transposed [k][b]  (2 KB)
  __shared__ float Bt[KT][OT];  // kernel tile [k][o]         (16 KB)
  const int bid = blockIdx.x;
  const int t   = threadIdx.x;

  if (bid < NGEMM) {
    // ---- GEMM partial: partial[ks][b][o] = sum_{k in chunk, ascending} A[b,k]*K[k,o]
    const int ot = bid & 3, bt = (bid >> 2) & 3, ks = bid >> 4;
    const int tx = t & 63;        // 64 o-groups of 4 cols
    const int ty = t >> 6;        // 4 b-groups of 8 rows
    f4 acc[8] = {{0,0,0,0},{0,0,0,0},{0,0,0,0},{0,0,0,0},
                 {0,0,0,0},{0,0,0,0},{0,0,0,0},{0,0,0,0}};
    const float* Ab = mem + 512 * F;   // A = (128 x 4096) row-major

    for (int kc = 0; kc < KCHUNK; kc += KT) {
      const int k0 = ks * KCHUNK + kc;
      // stage A: 32 rows x 16 k, transposed into LDS (1 f2 per thread)
      {
        const int b_l = t >> 3;          // 0..31
        const int k_l = (t & 7) * 2;     // 0..14 (even)
        f2 v = *(const f2*)(Ab + (size_t)(bt * BT + b_l) * KK + k0 + k_l);
        At[k_l][b_l]     = v.x;
        At[k_l + 1][b_l] = v.y;
      }
      // stage B: 16 k-rows x 256 cols = 1024 float4, 4 per thread (coalesced)
#pragma unroll
      for (int i = 0; i < 4; ++i) {
        const int fid = t + i * 256;
        const int r = fid >> 6, c4 = fid & 63;
        *(f4*)&Bt[r][c4 * 4] =
            *(const f4*)(kern + (size_t)(k0 + r) * F + ot * OT + c4 * 4);
      }
      __syncthreads();
#pragma unroll
      for (int k = 0; k < KT; ++k) {
        // A reads broadcast across the wave (all lanes share ty)
        f4 a0 = *(const f4*)&At[k][ty * 8];
        f4 a1 = *(const f4*)&At[k][ty * 8 + 4];
        // B read: 64 consecutive float4 across the wave -> full-rate
        f4 bv = *(const f4*)&Bt[k][tx * 4];
        acc[0] += a0.x * bv;
        acc[1] += a0.y * bv;
        acc[2] += a0.z * bv;
        acc[3] += a0.w * bv;
        acc[4] += a1.x * bv;
        acc[5] += a1.y * bv;
        acc[6] += a1.z * bv;
        acc[7] += a1.w * bv;
      }
      __syncthreads();
    }
    float* p = partial + ((size_t)ks * NB + bt * BT + ty * 8) * F + ot * OT + tx * 4;
#pragma unroll
    for (int i = 0; i < 8; ++i) *(f4*)(p + (size_t)i * F) = acc[i];
    return;
  }

  // ---- bulk writer: pure gather, 4 output rows per block, NT stores.
  const int base = (bid - NGEMM) * 4;
#pragma unroll
  for (int r = 0; r < 4; ++r) {
    const int gid = base + r;
    const int b = gid >> 10, row = gid & 1023;
    const float* src;
    if (row < 512) {
      const int lim1 = 511 - b;                     // original conv rows kept
      if (row >= lim1) continue;                    // comp row -> comp_scatter
      src = mem + (size_t)(b + 1 + row) * F;
    } else {
      const int r2 = row - 512;
      const int c2 = 508 - 4 * b;                   // original short rows kept
      src = (r2 < c2) ? (mem + (size_t)(516 + 4 * b + r2) * F)
                      : (inputs + (size_t)(r2 - c2) * F);
    }
    const f4 v = *(const f4*)(src + t * 4);
    __builtin_nontemporal_store(v, (f4*)(out + (size_t)gid * F + t * 4));
  }
}

// K2: reduce the KSPLIT partials for comp row c in-register (bias first, then
// ks ascending -> bit-identical to prior passing rounds), then NT-scatter the
// row to every output sample containing it: out[b][511-b+c] = comp[c], b >= c.
// grid: 1024 blocks = (c: 128) x (jb: 8 chunks of 16 b-values).
__global__ __launch_bounds__(256) void comp_scatter(
    const float* __restrict__ partial, const float* __restrict__ bias,
    float* __restrict__ out)
{
  const int bid = blockIdx.x;
  const int c  = bid >> 3;        // comp row 0..127
  const int jb = bid & 7;         // b-chunk
  const int b0 = jb * 16;
  if (b0 + 15 < c) return;        // no b >= c in this chunk

  const int t = threadIdx.x;
  f4 s = *(const f4*)(bias + t * 4);
#pragma unroll
  for (int ks = 0; ks < KSPLIT; ++ks)
    s += *(const f4*)(partial + ((size_t)ks * NB + c) * F + t * 4);

  const int blo = (b0 > c) ? b0 : c;
  const int bhi = (b0 + 15 < 127) ? (b0 + 15) : 127;
  for (int b = blo; b <= bhi; ++b) {
    float* dst = out + ((size_t)b * 1024 + (511 - b + c)) * F + t * 4;
    __builtin_nontemporal_store(s, (f4*)dst);
  }
}

extern "C" void kernel_launch(void* const* d_in, const int* in_sizes, int n_in,
                              void* d_out, int out_size, void* d_ws, size_t ws_size,
                              hipStream_t stream) {
  const float* inputs = (const float*)d_in[0];   // (128,4,1024)
  const float* memory = (const float*)d_in[1];   // (1024,1024)
  const float* kern   = (const float*)d_in[2];   // (4,1024,1024)
  const float* bias   = (const float*)d_in[3];   // (1024,)
  float* out = (float*)d_out;                    // (128,1024,1024)

  float* partial = (float*)d_ws;                 // KSPLIT*128*1024 floats = 4 MiB

  fused_bulk<<<dim3(NWRITE + NGEMM), 256, 0, stream>>>(inputs, memory, kern,
                                                       partial, out);
  comp_scatter<<<dim3(1024), 256, 0, stream>>>(partial, bias, out);
}